// Round 4
// baseline (437.878 us; speedup 1.0000x reference)
//
#include <hip/hip_runtime.h>
#include <hip/hip_bf16.h>

#define MAX_DIST 32.0f
#define BOX 129
#define BOX3 (129 * 129 * 129)

// Pass 2: per-cell linked lists + compact worklist of occupied cells.
__global__ void __launch_bounds__(256) build_lists_kernel(
    const float* __restrict__ coords,
    int* __restrict__ head,
    int* __restrict__ next,
    int* __restrict__ wl,
    int* __restrict__ wl_cnt,
    int N) {
  int stride = gridDim.x * blockDim.x;
  for (int p = blockIdx.x * blockDim.x + threadIdx.x; p < N; p += stride) {
    float x = coords[3 * p + 0];
    float y = coords[3 * p + 1];
    float z = coords[3 * p + 2];
    // (c + 32) / 0.5 == (c + 32) * 2 (exact); round-half-even matches jnp.round
    int gx = __float2int_rn((x + MAX_DIST) * 2.0f);
    int gy = __float2int_rn((y + MAX_DIST) * 2.0f);
    int gz = __float2int_rn((z + MAX_DIST) * 2.0f);
    if ((unsigned)gx < BOX && (unsigned)gy < BOX && (unsigned)gz < BOX) {
      int cell = (gx * BOX + gy) * BOX + gz;
      int old = atomicExch(&head[cell], p);
      next[p] = old;
      if (old < 0) {  // first point to touch this cell: claim a worklist slot
        int s = atomicAdd(wl_cnt, 1);
        wl[s] = cell;
      }
    }
  }
}

// Pass 3: gather ONLY occupied cells (~300k of 2.15M). 8 lanes per cell;
// lane fp owns float4 fragment fp. 128B coalesced feature reads per point,
// one 128B plain store per cell. Empty cells stay at the memset zeros.
__global__ void __launch_bounds__(256) gather_wl_kernel(
    const int* __restrict__ head,
    const int* __restrict__ next,
    const int* __restrict__ wl,
    const int* __restrict__ wl_cnt,
    const float4* __restrict__ feats4,
    float4* __restrict__ grid4) {
  int cnt = *wl_cnt;
  long total = (long)cnt * 8;
  long stride = (long)gridDim.x * blockDim.x;
  for (long t = (long)blockIdx.x * blockDim.x + threadIdx.x; t < total; t += stride) {
    int wi = (int)(t >> 3);
    int fp = (int)(t & 7);
    int cell = wl[wi];
    float4 acc = make_float4(0.f, 0.f, 0.f, 0.f);
    for (int p = head[cell]; p >= 0; p = next[p]) {
      float4 v = feats4[(long)p * 8 + fp];
      acc.x += v.x; acc.y += v.y; acc.z += v.z; acc.w += v.w;
    }
    grid4[(long)cell * 8 + fp] = acc;
  }
}

// Fallback (round-1 proven): memset + direct atomics.
__global__ void __launch_bounds__(256) scatter_fallback_kernel(
    const float* __restrict__ coords,
    const float2* __restrict__ feats,
    float* __restrict__ grid,
    int N) {
  int total = N * 16;
  int stride = gridDim.x * blockDim.x;
  for (int t = blockIdx.x * blockDim.x + threadIdx.x; t < total; t += stride) {
    int p = t >> 4;
    int fp = t & 15;
    float x = coords[3 * p + 0];
    float y = coords[3 * p + 1];
    float z = coords[3 * p + 2];
    int gx = __float2int_rn((x + MAX_DIST) * 2.0f);
    int gy = __float2int_rn((y + MAX_DIST) * 2.0f);
    int gz = __float2int_rn((z + MAX_DIST) * 2.0f);
    if ((unsigned)gx < BOX && (unsigned)gy < BOX && (unsigned)gz < BOX) {
      float2 v = feats[(long)p * 16 + fp];
      long base = (((long)gx * BOX + gy) * BOX + gz) * 32 + 2 * fp;
      atomicAdd(&grid[base + 0], v.x);
      atomicAdd(&grid[base + 1], v.y);
    }
  }
}

static inline size_t pad256(size_t x) { return (x + 255) & ~(size_t)255; }

extern "C" void kernel_launch(void* const* d_in, const int* in_sizes, int n_in,
                              void* d_out, int out_size, void* d_ws, size_t ws_size,
                              hipStream_t stream) {
  const float* coords = (const float*)d_in[0];
  int N = in_sizes[0] / 3;  // 500000

  size_t head_b = pad256((size_t)BOX3 * sizeof(int));  // ~8.59 MB
  size_t next_b = pad256((size_t)N * sizeof(int));     // ~2.0 MB
  size_t cnt_b  = 256;
  size_t wl_b   = pad256((size_t)BOX3 * sizeof(int));  // ~8.59 MB
  size_t needed = head_b + next_b + cnt_b + wl_b;

  if (ws_size >= needed) {
    int* head   = (int*)d_ws;
    int* next   = (int*)((char*)d_ws + head_b);
    int* wl_cnt = (int*)((char*)d_ws + head_b + next_b);
    int* wl     = (int*)((char*)d_ws + head_b + next_b + cnt_b);

    // Re-init every call (ws/d_out are poisoned 0xAA before each replay).
    hipMemsetAsync(head, 0xFF, (size_t)BOX3 * sizeof(int), stream);  // -1
    hipMemsetAsync(wl_cnt, 0, sizeof(int), stream);
    hipMemsetAsync(d_out, 0, (size_t)out_size * sizeof(float), stream);

    int blocks2 = (N + 255) / 256;
    build_lists_kernel<<<blocks2, 256, 0, stream>>>(coords, head, next, wl, wl_cnt, N);

    gather_wl_kernel<<<4096, 256, 0, stream>>>(
        head, next, wl, wl_cnt, (const float4*)d_in[1], (float4*)d_out);
  } else {
    hipMemsetAsync(d_out, 0, (size_t)out_size * sizeof(float), stream);
    int total = N * 16;
    int blocks = 4096;
    if (blocks > (total + 255) / 256) blocks = (total + 255) / 256;
    scatter_fallback_kernel<<<blocks, 256, 0, stream>>>(
        coords, (const float2*)d_in[1], (float*)d_out, N);
  }
}